// Round 9
// baseline (117.326 us; speedup 1.0000x reference)
//
#include <hip/hip_runtime.h>
#include <hip/hip_bf16.h>
#include <stdint.h>

// NeighborhoodAttention1D: B=4, L=4096, C=512, H=16, hd=32, K=13
// pack W->frag-order bf16 ; GEMM1 (fp32-A fused-convert reg-staging, B direct) ;
// natt ; GEMM2 (bf16-A gll16 staging, B direct)

typedef __attribute__((ext_vector_type(8))) short short8;   // 8 x bf16 frag
typedef __attribute__((ext_vector_type(4))) float f32x4;    // MFMA C/D frag
typedef __attribute__((ext_vector_type(8))) unsigned short u16x8;
typedef __attribute__((ext_vector_type(4))) float float4v;

#define NB 4
#define NL 4096
#define NC 512
#define NH 16
#define HD 32
#define KW 13
#define KHALF 6
#define NM (NB*NL)   // 16384 rows

__device__ __forceinline__ float b2f(unsigned short u) {
  union { unsigned int i; float f; } x; x.i = ((unsigned int)u) << 16; return x.f;
}
__device__ __forceinline__ unsigned short f2b(float f) {
  __hip_bfloat16 h = __float2bfloat16(f);   // RNE
  return __builtin_bit_cast(unsigned short, h);
}
__device__ __forceinline__ void gll16(const unsigned short* g, unsigned short* l) {
  __builtin_amdgcn_global_load_lds(
      (const __attribute__((address_space(1))) void*)g,
      (__attribute__((address_space(3))) void*)l, 16, 0, 0);
}

// ------ pack W[K][N] (fp32) -> Bf fragment-ordered bf16 --------------------
// group g = (((tn*8 + kt)*2 + wn)*4 + nj)*2 + kb; lane; e(8):
//   n = tn*128 + wn*64 + nj*16 + (lane&15),  k = kt*64 + (kb*4+(lane>>4))*8 + e
__global__ __launch_bounds__(256)
void pack_bf(const float* __restrict__ W, unsigned short* __restrict__ Bf,
             int N, int ngroups) {
  int g = blockIdx.x * 256 + threadIdx.x;
  if (g >= ngroups) return;
  int lane = g & 63;
  int kb   = (g >> 6) & 1;
  int nj   = (g >> 7) & 3;
  int wn   = (g >> 9) & 1;
  int kt   = (g >> 10) & 7;
  int tn   = g >> 13;
  int n  = tn * 128 + wn * 64 + nj * 16 + (lane & 15);
  int k0 = kt * 64 + (kb * 4 + (lane >> 4)) * 8;
  u16x8 u;
  #pragma unroll
  for (int e = 0; e < 8; ++e) u[e] = f2b(W[(long)(k0 + e) * N + n]);
  ((u16x8*)Bf)[g] = u;
}

// ====== 128x128 bf16-MFMA GEMM, A-only LDS 32KB dbuf, B frag-direct ========
// IN_F32=1: A is fp32, staged global->regs->cvt->ds_write (fuses the x->bf16
//   conversion kernel into GEMM1; R8's standalone cvt was a 96MB/15us HBM
//   round trip). Reg-staging also lets the LDS swizzle be applied on the
//   write side directly (rule 21 both-sides).
// IN_F32=0: A bf16 via global_load_lds (R8's proven path + manual VM ledger).
// K = 512 -> 8 K-tiles of 64. 4 waves (2Mx2N), per-wave 64x64 = acc[4][4].
// Per-iter (IN_F32): LDBG(kt) | schedbar | issue A(kt+2) f32 loads | LDA |
//   lgkm0 | MFMA (compiler bf-wait = vmcnt(8), A-loads stay in flight) |
//   BAR | cvt+ds_write A(kt+2) (compiler vmcnt-waits) | lgkm0 | BAR.
// Swizzle: 16B-chunk ^= (row&7) within 128B rows (verified 0 conflicts).

__device__ __forceinline__ void stage_tileA(const unsigned short* __restrict__ G,
                                            long rowBase, int K, int kt,
                                            unsigned short* ldsDst, int tid) {
  int r  = tid >> 3;                       // 0..31
  int ch = (tid & 7) ^ (r & 7);            // inverse-swizzled source chunk
  const unsigned short* s0 = G + (rowBase + r) * (long)K + kt * 64 + ch * 8;
  unsigned short* d0 = ldsDst + tid * 8;
  #pragma unroll
  for (int q = 0; q < 4; ++q)              // rows r, r+32, r+64, r+96
    gll16(s0 + (long)32 * q * K, d0 + 2048 * q);
}

// fp32 A: thread -> row r = tid>>3 (+32q), 8-float chunk ch = tid&7.
// Lanes 0..7 cover one 256B row contiguously -> fully coalesced dwordx4 x2.
__device__ __forceinline__ void loadA_f32(const float* __restrict__ G,
                                          long rowBase, int K, int kt,
                                          int tid, float4v (&ra)[8]) {
  int r  = tid >> 3;
  int ch = tid & 7;
  const float* s = G + (rowBase + r) * (long)K + kt * 64 + ch * 8;
  #pragma unroll
  for (int q = 0; q < 4; ++q) {
    const float4v* p = (const float4v*)(s + (long)32 * q * K);
    ra[2 * q]     = p[0];
    ra[2 * q + 1] = p[1];
  }
}
__device__ __forceinline__ void writeA_bf16(unsigned short* ldsA, int tid,
                                            const float4v (&ra)[8]) {
  int r  = tid >> 3;
  int ch = tid & 7;
  #pragma unroll
  for (int q = 0; q < 4; ++q) {
    int row = r + 32 * q;
    const float4v a = ra[2 * q], b = ra[2 * q + 1];
    u16x8 u;
    u[0] = f2b(a.x); u[1] = f2b(a.y); u[2] = f2b(a.z); u[3] = f2b(a.w);
    u[4] = f2b(b.x); u[5] = f2b(b.y); u[6] = f2b(b.z); u[7] = f2b(b.w);
    *(u16x8*)(ldsA + row * 64 + ((ch ^ (row & 7)) * 8)) = u;
  }
}

#define BAR() __builtin_amdgcn_s_barrier()
#define LGK0() do { asm volatile("s_waitcnt lgkmcnt(0)" ::: "memory"); \
                    __builtin_amdgcn_sched_barrier(0); } while (0)
#define VM(N) asm volatile("s_waitcnt vmcnt(" #N ")" ::: "memory")
#define SCHED0() __builtin_amdgcn_sched_barrier(0)

// af[ii][kb] <- A row wm*64 + ii*16 + lr, 16B chunk (kb*4+lk)^(row&7)
#define LDA(ABASE) do { \
  const char* _ba = (const char*)(ABASE); \
  _Pragma("unroll") for (int ii = 0; ii < 4; ++ii) { \
    int _row = wm*64 + ii*16 + lr; \
    _Pragma("unroll") for (int kb = 0; kb < 2; ++kb) \
      af[ii][kb] = *(const short8*)(_ba + _row*128 + (((kb*4+lk) ^ lr7) * 16)); \
  } \
} while (0)

// bf[nj][kb] <- packed B frags for K-tile KT (8 coalesced 16B loads, L2-hot)
#define LDBG(KT) do { \
  const short8* _bp = (const short8*)(Bfw + (long)(KT) * 8192) + lane; \
  _Pragma("unroll") for (int nj = 0; nj < 4; ++nj) \
    _Pragma("unroll") for (int kb = 0; kb < 2; ++kb) \
      bf[nj][kb] = _bp[(nj*2 + kb) * 64]; \
} while (0)

#define MMA_ALL() do { \
  __builtin_amdgcn_s_setprio(1); \
  _Pragma("unroll") for (int ii = 0; ii < 4; ++ii) \
    _Pragma("unroll") for (int jj = 0; jj < 4; ++jj) \
      _Pragma("unroll") for (int kb = 0; kb < 2; ++kb) \
        acc[ii][jj] = __builtin_amdgcn_mfma_f32_16x16x32_bf16( \
            af[ii][kb], bf[jj][kb], acc[ii][jj], 0, 0, 0); \
  __builtin_amdgcn_s_setprio(0); \
} while (0)

// bf16-A path K-tile (R8 ledger: VM(4) -> A(kt+1)+B(kt) retired)
#define GTILE_BF16(ABUF, KT, STG, VMARG) do { \
  LDBG(KT); \
  LDA(ABUF); \
  LGK0(); \
  BAR(); \
  if (STG) stage_tileA(Agh, mBase, K, (KT) + 2, ABUF, tid); \
  VMARG; \
  MMA_ALL(); \
  BAR(); \
} while (0)

// fp32-A path K-tile
#define GTILE_F32(ABUF, KT, STG) do { \
  LDBG(KT); \
  SCHED0(); /* pin: B loads issue before A loads (bf wait leaves A in flight) */ \
  if (STG) loadA_f32(Agf, mBase, K, (KT) + 2, tid, ra); \
  LDA(ABUF); \
  LGK0(); \
  MMA_ALL(); \
  BAR(); \
  if (STG) { writeA_bf16(ABUF, tid, ra); LGK0(); } \
  BAR(); \
} while (0)

template<int OUT_BF16, int IN_F32>
__global__ __launch_bounds__(256, 3)
void gemm128(const void* __restrict__ Ag,
             const unsigned short* __restrict__ Bf,
             const float* __restrict__ bias,
             void* __restrict__ Cout,
             int M, int N, int K, int tilesN) {
  __shared__ __align__(16) unsigned short lds[16384];   // 32 KiB (A dbuf)

  int tid = threadIdx.x;
  int nwg = gridDim.x;                   // 1536 / 512, both %8==0
  int cpx = nwg >> 3;
  int wg  = ((int)blockIdx.x & 7) * cpx + ((int)blockIdx.x >> 3);  // XCD swizzle
  int tm = wg / tilesN, tn = wg % tilesN;
  long mBase = (long)tm * 128;
  long nBase = (long)tn * 128;

  int lane = tid & 63, wave = tid >> 6;
  int wm = wave >> 1;          // 0..1 : M half (64 rows)
  int wn = wave & 1;           // 0..1 : N half (64 cols)
  int lr = lane & 15, lk = lane >> 4, lr7 = lr & 7;

  const unsigned short* Bfw = Bf + (long)tn * 65536 + wn * 4096;
  const unsigned short* Agh = (const unsigned short*)Ag;  // bf16 view
  const float*          Agf = (const float*)Ag;           // fp32 view

  unsigned short* A0 = lds;              // buf0 A (128x64 bf16)
  unsigned short* A1 = lds + 8192;       // buf1 A

  short8 af[4][2], bf[4][2];
  f32x4 acc[4][4];

  if constexpr (IN_F32) {
    float4v ra[8];
    // prologue: T0 -> buf0, T1 -> buf1 (compiler vmcnt-waits each)
    loadA_f32(Agf, mBase, K, 0, tid, ra);
    writeA_bf16(A0, tid, ra);
    loadA_f32(Agf, mBase, K, 1, tid, ra);
    writeA_bf16(A1, tid, ra);
    LGK0(); BAR();

    #pragma unroll
    for (int i = 0; i < 4; ++i)
      #pragma unroll
      for (int j = 0; j < 4; ++j) acc[i][j] = (f32x4){0.f, 0.f, 0.f, 0.f};

    #pragma unroll 1
    for (int i = 0; i < 3; ++i) {
      GTILE_F32(A0, 2*i,     true);
      GTILE_F32(A1, 2*i + 1, true);
    }
    GTILE_F32(A0, 6, false);
    GTILE_F32(A1, 7, false);
  } else {
    // prologue: A(0)->buf0, A(1)->buf1 via global_load_lds
    stage_tileA(Agh, mBase, K, 0, A0, tid);
    stage_tileA(Agh, mBase, K, 1, A1, tid);
    VM(4);                       // A(0) landed (A(1)'s 4 in flight)
    BAR();

    #pragma unroll
    for (int i = 0; i < 4; ++i)
      #pragma unroll
      for (int j = 0; j < 4; ++j) acc[i][j] = (f32x4){0.f, 0.f, 0.f, 0.f};

    #pragma unroll 1
    for (int i = 0; i < 3; ++i) {
      GTILE_BF16(A0, 2*i,     true, VM(4));
      GTILE_BF16(A1, 2*i + 1, true, VM(4));
    }
    GTILE_BF16(A0, 6, false, VM(0));
    GTILE_BF16(A1, 7, false, VM(0));
  }

  // ---- epilogue: C/D layout col = lane&15, row = (lane>>4)*4 + r --------
  long rowb = mBase + wm * 64 + (lane >> 4) * 4;
  int  colb = (int)nBase + wn * 64 + lr;
  if (OUT_BF16) {
    unsigned short* C = (unsigned short*)Cout;
    #pragma unroll
    for (int mi = 0; mi < 4; ++mi)
      #pragma unroll
      for (int nj = 0; nj < 4; ++nj) {
        int col = colb + nj * 16;
        float bv = bias[col];
        #pragma unroll
        for (int r = 0; r < 4; ++r)
          C[(rowb + mi * 16 + r) * (long)N + col] = f2b(acc[mi][nj][r] + bv);
      }
  } else {
    float* C = (float*)Cout;
    #pragma unroll
    for (int mi = 0; mi < 4; ++mi)
      #pragma unroll
      for (int nj = 0; nj < 4; ++nj) {
        int col = colb + nj * 16;
        float bv = bias[col];
        #pragma unroll
        for (int r = 0; r < 4; ++r)
          C[(rowb + mi * 16 + r) * (long)N + col] = acc[mi][nj][r] + bv;
      }
  }
}

// ---------------- neighborhood attention: 1 thread per (b,l,h) ------------
__global__ __launch_bounds__(256)
void natt(const unsigned short* __restrict__ qkv, const float* __restrict__ rpb,
          unsigned short* __restrict__ out) {
  int tid = blockIdx.x * 256 + threadIdx.x;
  int h = tid & 15;
  int l = (tid >> 4) & (NL - 1);
  int b = tid >> 16;
  const float scale = 0.17677669529663687f;

  long qb = ((long)(b * NL + l) * 3) * NC + h * HD;
  float q[HD];
  {
    const u16x8* q8 = (const u16x8*)(qkv + qb);
    #pragma unroll
    for (int w = 0; w < 4; ++w) {
      u16x8 u = q8[w];
      #pragma unroll
      for (int e = 0; e < 8; ++e) q[w * 8 + e] = b2f(u[e]) * scale;
    }
  }

  int ni = l - KHALF;
  if (ni < 0) ni = 0;
  if (ni > NL - KW) ni = NL - KW;
  const float* rb = rpb + h * (2 * KW - 1) + (ni - l + KW - 1);

  float p[KW];
  float mx = -1e30f;
  #pragma unroll
  for (int j = 0; j < KW; ++j) {
    long kb = ((long)(b * NL + ni + j) * 3 + 1) * NC + h * HD;
    const u16x8* k8 = (const u16x8*)(qkv + kb);
    float s = 0.f;
    #pragma unroll
    for (int w = 0; w < 4; ++w) {
      u16x8 u = k8[w];
      #pragma unroll
      for (int e = 0; e < 8; ++e) s += q[w * 8 + e] * b2f(u[e]);
    }
    s += rb[j];
    p[j] = s;
    mx = fmaxf(mx, s);
  }

  float sum = 0.f;
  #pragma unroll
  for (int j = 0; j < KW; ++j) { p[j] = __expf(p[j] - mx); sum += p[j]; }
  float inv = 1.0f / sum;

  float o[HD];
  #pragma unroll
  for (int d = 0; d < HD; ++d) o[d] = 0.f;
  #pragma unroll
  for (int j = 0; j < KW; ++j) {
    long vb = ((long)(b * NL + ni + j) * 3 + 2) * NC + h * HD;
    const u16x8* v8 = (const u16x8*)(qkv + vb);
    float wj = p[j] * inv;
    #pragma unroll
    for (int w = 0; w < 4; ++w) {
      u16x8 u = v8[w];
      #pragma unroll
      for (int e = 0; e < 8; ++e) o[w * 8 + e] += wj * b2f(u[e]);
    }
  }

  unsigned short* op = out + (long)(b * NL + l) * NC + h * HD;
  #pragma unroll
  for (int w = 0; w < 4; ++w) {
    u16x8 u;
    #pragma unroll
    for (int e = 0; e < 8; ++e) u[e] = f2b(o[w * 8 + e]);
    *((u16x8*)(op + w * 8)) = u;
  }
}

// ---------------------------------------------------------------------------
extern "C" void kernel_launch(void* const* d_in, const int* in_sizes, int n_in,
                              void* d_out, int out_size, void* d_ws, size_t ws_size,
                              hipStream_t stream) {
  const float* x      = (const float*)d_in[0];
  const float* qkv_w  = (const float*)d_in[1];
  const float* qkv_b  = (const float*)d_in[2];
  const float* rpb    = (const float*)d_in[3];
  const float* proj_w = (const float*)d_in[4];
  const float* proj_b = (const float*)d_in[5];
  float* out = (float*)d_out;

  char* ws = (char*)d_ws;
  unsigned short* Bf1  = (unsigned short*)(ws);              //  1,572,864 B
  unsigned short* Bf2  = (unsigned short*)(ws + 1572864);    //    524,288 B
  unsigned short* qkvo = (unsigned short*)(ws + 2097152);    // 50,331,648 B
  unsigned short* attno= (unsigned short*)(ws + 52428800);   // 16,777,216 B

  // pack weights into MFMA-fragment order
  pack_bf<<<dim3(384), dim3(256), 0, stream>>>(qkv_w, Bf1, 1536, 98304);
  pack_bf<<<dim3(128), dim3(256), 0, stream>>>(proj_w, Bf2, 512, 32768);
  // qkv = x @ qkv_w + b  (fp32 A fused-convert; bf16 out): 1536 blocks
  gemm128<1, 1><<<dim3(1536), dim3(256), 0, stream>>>(x, Bf1, qkv_b, qkvo,
                                                      NM, 1536, 512, 12);
  natt<<<dim3(1024), dim3(256), 0, stream>>>(qkvo, rpb, attno);
  // out = attn @ proj_w + b  (bf16 A via gll16; fp32 out): 512 blocks
  gemm128<0, 0><<<dim3(512), dim3(256), 0, stream>>>(attno, Bf2, proj_b, out,
                                                     NM, 512, 512, 4);
}

// Round 10
// 103.436 us; speedup vs baseline: 1.1343x; 1.1343x over previous
//
#include <hip/hip_runtime.h>
#include <hip/hip_bf16.h>
#include <stdint.h>

// NeighborhoodAttention1D: B=4, L=4096, C=512, H=16, hd=32, K=13
// pack W->frag-order bf16 ; GEMM1 (fp32-A-in-LDS fused convert, B direct) ;
// natt ; GEMM2 (R8-verbatim bf16-A gll16 path, B direct)

typedef __attribute__((ext_vector_type(8))) short short8;   // 8 x bf16 frag
typedef __attribute__((ext_vector_type(4))) float f32x4;    // MFMA C/D frag
typedef __attribute__((ext_vector_type(8))) unsigned short u16x8;
typedef __attribute__((ext_vector_type(4))) float float4v;

#define NB 4
#define NL 4096
#define NC 512
#define NH 16
#define HD 32
#define KW 13
#define KHALF 6
#define NM (NB*NL)   // 16384 rows

__device__ __forceinline__ float b2f(unsigned short u) {
  union { unsigned int i; float f; } x; x.i = ((unsigned int)u) << 16; return x.f;
}
__device__ __forceinline__ unsigned short f2b(float f) {
  __hip_bfloat16 h = __float2bfloat16(f);   // RNE
  return __builtin_bit_cast(unsigned short, h);
}
__device__ __forceinline__ void gll16(const void* g, unsigned short* l) {
  __builtin_amdgcn_global_load_lds(
      (const __attribute__((address_space(1))) void*)g,
      (__attribute__((address_space(3))) void*)l, 16, 0, 0);
}
__device__ __forceinline__ short8 pack8(float4v lo, float4v hi) {
  u16x8 u;
  u[0] = f2b(lo.x); u[1] = f2b(lo.y); u[2] = f2b(lo.z); u[3] = f2b(lo.w);
  u[4] = f2b(hi.x); u[5] = f2b(hi.y); u[6] = f2b(hi.z); u[7] = f2b(hi.w);
  return __builtin_bit_cast(short8, u);
}

// ------ pack W[K][N] (fp32) -> Bf fragment-ordered bf16 --------------------
// group g = (((tn*8 + kt)*2 + wn)*4 + nj)*2 + kb; lane; e(8):
//   n = tn*128 + wn*64 + nj*16 + (lane&15),  k = kt*64 + (kb*4+(lane>>4))*8 + e
__global__ __launch_bounds__(256)
void pack_bf(const float* __restrict__ W, unsigned short* __restrict__ Bf,
             int N, int ngroups) {
  int g = blockIdx.x * 256 + threadIdx.x;
  if (g >= ngroups) return;
  int lane = g & 63;
  int kb   = (g >> 6) & 1;
  int nj   = (g >> 7) & 3;
  int wn   = (g >> 9) & 1;
  int kt   = (g >> 10) & 7;
  int tn   = g >> 13;
  int n  = tn * 128 + wn * 64 + nj * 16 + (lane & 15);
  int k0 = kt * 64 + (kb * 4 + (lane >> 4)) * 8;
  u16x8 u;
  #pragma unroll
  for (int e = 0; e < 8; ++e) u[e] = f2b(W[(long)(k0 + e) * N + n]);
  ((u16x8*)Bf)[g] = u;
}

#define BAR() __builtin_amdgcn_s_barrier()
#define LGK0() do { asm volatile("s_waitcnt lgkmcnt(0)" ::: "memory"); \
                    __builtin_amdgcn_sched_barrier(0); } while (0)
#define VM(N) asm volatile("s_waitcnt vmcnt(" #N ")" ::: "memory")

// bf[nj][kb] <- packed B frags for K-tile KT (8 coalesced 16B loads, L2-hot)
#define LDBG(KT) do { \
  const short8* _bp = (const short8*)(Bfw + (long)(KT) * 8192) + lane; \
  _Pragma("unroll") for (int nj = 0; nj < 4; ++nj) \
    _Pragma("unroll") for (int kb = 0; kb < 2; ++kb) \
      bf[nj][kb] = _bp[(nj*2 + kb) * 64]; \
} while (0)

#define MMA_ALL() do { \
  __builtin_amdgcn_s_setprio(1); \
  _Pragma("unroll") for (int ii = 0; ii < 4; ++ii) \
    _Pragma("unroll") for (int jj = 0; jj < 4; ++jj) \
      _Pragma("unroll") for (int kb = 0; kb < 2; ++kb) \
        acc[ii][jj] = __builtin_amdgcn_mfma_f32_16x16x32_bf16( \
            af[ii][kb], bf[jj][kb], acc[ii][jj], 0, 0, 0); \
  __builtin_amdgcn_s_setprio(0); \
} while (0)

// ============ GEMM1: fp32 A staged to LDS, cvt on LDS->reg read ============
// A fp32 tile [128 rows][64 floats] = 32KB/K-tile, dbuf 64KB -> 2 blocks/CU.
// Row = 16 granules of 16B; granule g stored at slot g^(row&15) (bijective;
// source-pre-swizzled for gll16's linear dest, rule 21). Read: frag (kb,lk)
// = granules 2*(kb*4+lk), +1 -> two b128 at slots (g^lr),(g^1^lr); wave
// spreads 4 lanes/slot over 16 slots = min 8 clks, conflict-free.
// Per iter kt (buf kt&1): LDBG(kt) | LDA_F32+cvt | lgkm0 | BAR |
//   stage A(kt+2) 8 gll | VM(8) [retires A(kt+1)+B(kt)] | MFMA | BAR.
// Tails kt=6,7: no stage, VM(0). WAR: stage after BAR ending buf reads (R8).

__device__ __forceinline__ void stageA_f32(const float* __restrict__ G,
                                           long rowBase, int K, int kt,
                                           unsigned short* ldsDst, int tid) {
  int lane = tid & 63, w = tid >> 6;
  int rsub = lane >> 4;                    // 0..3
  int slot = lane & 15;
  #pragma unroll
  for (int q = 0; q < 8; ++q) {
    int row = w * 32 + q * 4 + rsub;
    int g = slot ^ (row & 15);             // inverse-swizzled source granule
    const float* src = G + (rowBase + row) * (long)K + kt * 64 + g * 4;
    gll16(src, ldsDst + row * 128 + slot * 8);   // dest = base + lane*16B
  }
}

// af[ii][kb] <- fp32 frag from LDS, cvt to bf16
#define LDA_F32(ABASE) do { \
  const char* _ba = (const char*)(ABASE); \
  _Pragma("unroll") for (int ii = 0; ii < 4; ++ii) { \
    int _row = wm*64 + ii*16 + lr; \
    const char* _rp = _ba + _row*256; \
    _Pragma("unroll") for (int kb = 0; kb < 2; ++kb) { \
      int _g = (kb*4 + lk) * 2; \
      float4v _lo = *(const float4v*)(_rp + ((_g ^ lr) * 16)); \
      float4v _hi = *(const float4v*)(_rp + (((_g+1) ^ lr) * 16)); \
      af[ii][kb] = pack8(_lo, _hi); \
    } \
  } \
} while (0)

#define G1TILE(ABUF, KT, STG, VMARG) do { \
  LDBG(KT); \
  LDA_F32(ABUF); \
  LGK0(); \
  BAR(); \
  if (STG) stageA_f32(Ag, mBase, K, (KT) + 2, ABUF, tid); \
  VMARG; \
  MMA_ALL(); \
  BAR(); \
} while (0)

__global__ __launch_bounds__(256, 2)
void gemm128f(const float* __restrict__ Ag,
              const unsigned short* __restrict__ Bf,
              const float* __restrict__ bias,
              unsigned short* __restrict__ Cout,
              int M, int N, int K, int tilesN) {
  __shared__ __align__(16) unsigned short lds[32768];   // 64 KiB (fp32 A dbuf)

  int tid = threadIdx.x;
  int nwg = gridDim.x;
  int cpx = nwg >> 3;
  int wg  = ((int)blockIdx.x & 7) * cpx + ((int)blockIdx.x >> 3);  // XCD swizzle
  int tm = wg / tilesN, tn = wg % tilesN;
  long mBase = (long)tm * 128;
  long nBase = (long)tn * 128;

  int lane = tid & 63, wave = tid >> 6;
  int wm = wave >> 1, wn = wave & 1;
  int lr = lane & 15, lk = lane >> 4;

  const unsigned short* Bfw = Bf + (long)tn * 65536 + wn * 4096;

  unsigned short* A0 = lds;              // buf0 A (128x64 fp32 = 32KB)
  unsigned short* A1 = lds + 16384;      // buf1 A

  f32x4 acc[4][4];
  #pragma unroll
  for (int i = 0; i < 4; ++i)
    #pragma unroll
    for (int j = 0; j < 4; ++j) acc[i][j] = (f32x4){0.f, 0.f, 0.f, 0.f};

  short8 af[4][2], bf[4][2];

  // prologue: A(0)->buf0, A(1)->buf1 (16 gll16/thread)
  stageA_f32(Ag, mBase, K, 0, A0, tid);
  stageA_f32(Ag, mBase, K, 1, A1, tid);
  VM(8);                       // A(0) landed (A(1)'s 8 in flight)
  BAR();

  #pragma unroll 1
  for (int i = 0; i < 3; ++i) {
    G1TILE(A0, 2*i,     true, VM(8));
    G1TILE(A1, 2*i + 1, true, VM(8));
  }
  G1TILE(A0, 6, false, VM(0));
  G1TILE(A1, 7, false, VM(0));

  // epilogue: C/D layout col = lane&15, row = (lane>>4)*4 + r ; bf16 out
  long rowb = mBase + wm * 64 + (lane >> 4) * 4;
  int  colb = (int)nBase + wn * 64 + lr;
  #pragma unroll
  for (int mi = 0; mi < 4; ++mi)
    #pragma unroll
    for (int nj = 0; nj < 4; ++nj) {
      int col = colb + nj * 16;
      float bv = bias[col];
      #pragma unroll
      for (int r = 0; r < 4; ++r)
        Cout[(rowb + mi * 16 + r) * (long)N + col] = f2b(acc[mi][nj][r] + bv);
    }
}

// ============ GEMM2: R8-verbatim bf16-A gll16 path, fp32 out ===============
__device__ __forceinline__ void stage_tileA(const unsigned short* __restrict__ G,
                                            long rowBase, int K, int kt,
                                            unsigned short* ldsDst, int tid) {
  int r  = tid >> 3;                       // 0..31
  int ch = (tid & 7) ^ (r & 7);            // inverse-swizzled source chunk
  const unsigned short* s0 = G + (rowBase + r) * (long)K + kt * 64 + ch * 8;
  unsigned short* d0 = ldsDst + tid * 8;
  #pragma unroll
  for (int q = 0; q < 4; ++q)              // rows r, r+32, r+64, r+96
    gll16(s0 + (long)32 * q * K, d0 + 2048 * q);
}

#define LDA_B16(ABASE) do { \
  const char* _ba = (const char*)(ABASE); \
  _Pragma("unroll") for (int ii = 0; ii < 4; ++ii) { \
    int _row = wm*64 + ii*16 + lr; \
    _Pragma("unroll") for (int kb = 0; kb < 2; ++kb) \
      af[ii][kb] = *(const short8*)(_ba + _row*128 + (((kb*4+lk) ^ lr7) * 16)); \
  } \
} while (0)

#define G2TILE(ABUF, KT, STG, VMARG) do { \
  LDBG(KT); \
  LDA_B16(ABUF); \
  LGK0(); \
  BAR(); \
  if (STG) stage_tileA(Ag, mBase, K, (KT) + 2, ABUF, tid); \
  VMARG; \
  MMA_ALL(); \
  BAR(); \
} while (0)

__global__ __launch_bounds__(256, 3)
void gemm128b(const unsigned short* __restrict__ Ag,
              const unsigned short* __restrict__ Bf,
              const float* __restrict__ bias,
              float* __restrict__ Cout,
              int M, int N, int K, int tilesN) {
  __shared__ __align__(16) unsigned short lds[16384];   // 32 KiB (A dbuf)

  int tid = threadIdx.x;
  int nwg = gridDim.x;
  int cpx = nwg >> 3;
  int wg  = ((int)blockIdx.x & 7) * cpx + ((int)blockIdx.x >> 3);  // XCD swizzle
  int tm = wg / tilesN, tn = wg % tilesN;
  long mBase = (long)tm * 128;
  long nBase = (long)tn * 128;

  int lane = tid & 63, wave = tid >> 6;
  int wm = wave >> 1, wn = wave & 1;
  int lr = lane & 15, lk = lane >> 4, lr7 = lr & 7;

  const unsigned short* Bfw = Bf + (long)tn * 65536 + wn * 4096;

  unsigned short* A0 = lds;              // buf0 A (128x64 bf16)
  unsigned short* A1 = lds + 8192;       // buf1 A

  f32x4 acc[4][4];
  #pragma unroll
  for (int i = 0; i < 4; ++i)
    #pragma unroll
    for (int j = 0; j < 4; ++j) acc[i][j] = (f32x4){0.f, 0.f, 0.f, 0.f};

  short8 af[4][2], bf[4][2];

  stage_tileA(Ag, mBase, K, 0, A0, tid);
  stage_tileA(Ag, mBase, K, 1, A1, tid);
  VM(4);                       // A(0) landed (A(1)'s 4 in flight)
  BAR();

  #pragma unroll 1
  for (int i = 0; i < 3; ++i) {
    G2TILE(A0, 2*i,     true, VM(4));
    G2TILE(A1, 2*i + 1, true, VM(4));
  }
  G2TILE(A0, 6, false, VM(0));
  G2TILE(A1, 7, false, VM(0));

  long rowb = mBase + wm * 64 + (lane >> 4) * 4;
  int  colb = (int)nBase + wn * 64 + lr;
  #pragma unroll
  for (int mi = 0; mi < 4; ++mi)
    #pragma unroll
    for (int nj = 0; nj < 4; ++nj) {
      int col = colb + nj * 16;
      float bv = bias[col];
      #pragma unroll
      for (int r = 0; r < 4; ++r)
        Cout[(rowb + mi * 16 + r) * (long)N + col] = acc[mi][nj][r] + bv;
    }
}

// ---------------- neighborhood attention: 1 thread per (b,l,h) ------------
__global__ __launch_bounds__(256)
void natt(const unsigned short* __restrict__ qkv, const float* __restrict__ rpb,
          unsigned short* __restrict__ out) {
  int tid = blockIdx.x * 256 + threadIdx.x;
  int h = tid & 15;
  int l = (tid >> 4) & (NL - 1);
  int b = tid >> 16;
  const float scale = 0.17677669529663687f;

  long qb = ((long)(b * NL + l) * 3) * NC + h * HD;
  float q[HD];
  {
    const u16x8* q8 = (const u16x8*)(qkv + qb);
    #pragma unroll
    for (int w = 0; w < 4; ++w) {
      u16x8 u = q8[w];
      #pragma unroll
      for (int e = 0; e < 8; ++e) q[w * 8 + e] = b2f(u[e]) * scale;
    }
  }

  int ni = l - KHALF;
  if (ni < 0) ni = 0;
  if (ni > NL - KW) ni = NL - KW;
  const float* rb = rpb + h * (2 * KW - 1) + (ni - l + KW - 1);

  float p[KW];
  float mx = -1e30f;
  #pragma unroll
  for (int j = 0; j < KW; ++j) {
    long kb = ((long)(b * NL + ni + j) * 3 + 1) * NC + h * HD;
    const u16x8* k8 = (const u16x8*)(qkv + kb);
    float s = 0.f;
    #pragma unroll
    for (int w = 0; w < 4; ++w) {
      u16x8 u = k8[w];
      #pragma unroll
      for (int e = 0; e < 8; ++e) s += q[w * 8 + e] * b2f(u[e]);
    }
    s += rb[j];
    p[j] = s;
    mx = fmaxf(mx, s);
  }

  float sum = 0.f;
  #pragma unroll
  for (int j = 0; j < KW; ++j) { p[j] = __expf(p[j] - mx); sum += p[j]; }
  float inv = 1.0f / sum;

  float o[HD];
  #pragma unroll
  for (int d = 0; d < HD; ++d) o[d] = 0.f;
  #pragma unroll
  for (int j = 0; j < KW; ++j) {
    long vb = ((long)(b * NL + ni + j) * 3 + 2) * NC + h * HD;
    const u16x8* v8 = (const u16x8*)(qkv + vb);
    float wj = p[j] * inv;
    #pragma unroll
    for (int w = 0; w < 4; ++w) {
      u16x8 u = v8[w];
      #pragma unroll
      for (int e = 0; e < 8; ++e) o[w * 8 + e] += wj * b2f(u[e]);
    }
  }

  unsigned short* op = out + (long)(b * NL + l) * NC + h * HD;
  #pragma unroll
  for (int w = 0; w < 4; ++w) {
    u16x8 u;
    #pragma unroll
    for (int e = 0; e < 8; ++e) u[e] = f2b(o[w * 8 + e]);
    *((u16x8*)(op + w * 8)) = u;
  }
}

// ---------------------------------------------------------------------------
extern "C" void kernel_launch(void* const* d_in, const int* in_sizes, int n_in,
                              void* d_out, int out_size, void* d_ws, size_t ws_size,
                              hipStream_t stream) {
  const float* x      = (const float*)d_in[0];
  const float* qkv_w  = (const float*)d_in[1];
  const float* qkv_b  = (const float*)d_in[2];
  const float* rpb    = (const float*)d_in[3];
  const float* proj_w = (const float*)d_in[4];
  const float* proj_b = (const float*)d_in[5];
  float* out = (float*)d_out;

  char* ws = (char*)d_ws;
  unsigned short* Bf1  = (unsigned short*)(ws);              //  1,572,864 B
  unsigned short* Bf2  = (unsigned short*)(ws + 1572864);    //    524,288 B
  unsigned short* qkvo = (unsigned short*)(ws + 2097152);    // 50,331,648 B
  unsigned short* attno= (unsigned short*)(ws + 52428800);   // 16,777,216 B

  // pack weights into MFMA-fragment order
  pack_bf<<<dim3(384), dim3(256), 0, stream>>>(qkv_w, Bf1, 1536, 98304);
  pack_bf<<<dim3(128), dim3(256), 0, stream>>>(proj_w, Bf2, 512, 32768);
  // qkv = x @ qkv_w + b  (fp32 A in LDS, fused convert; bf16 out)
  gemm128f<<<dim3(1536), dim3(256), 0, stream>>>(x, Bf1, qkv_b, qkvo,
                                                 NM, 1536, 512, 12);
  natt<<<dim3(1024), dim3(256), 0, stream>>>(qkvo, rpb, attno);
  // out = attn @ proj_w + b  (bf16 A via gll16; fp32 out)
  gemm128b<<<dim3(512), dim3(256), 0, stream>>>(attno, Bf2, proj_b, out,
                                                NM, 512, 512, 4);
}

// Round 11
// 101.134 us; speedup vs baseline: 1.1601x; 1.0228x over previous
//
#include <hip/hip_runtime.h>
#include <hip/hip_bf16.h>
#include <stdint.h>

// NeighborhoodAttention1D: B=4, L=4096, C=512, H=16, hd=32, K=13
// pack W->frag-order bf16 ; GEMM1 (reg-staged fused fp32->bf16 convert,
// B direct, bf16-LDS) ; natt ; GEMM2 (R8-verbatim bf16 gll16 path)

typedef __attribute__((ext_vector_type(8))) short short8;   // 8 x bf16 frag
typedef __attribute__((ext_vector_type(4))) float f32x4;    // MFMA C/D frag
typedef __attribute__((ext_vector_type(8))) unsigned short u16x8;
typedef __attribute__((ext_vector_type(4))) float float4v;

#define NB 4
#define NL 4096
#define NC 512
#define NH 16
#define HD 32
#define KW 13
#define KHALF 6
#define NM (NB*NL)   // 16384 rows

__device__ __forceinline__ float b2f(unsigned short u) {
  union { unsigned int i; float f; } x; x.i = ((unsigned int)u) << 16; return x.f;
}
__device__ __forceinline__ unsigned short f2b(float f) {
  __hip_bfloat16 h = __float2bfloat16(f);   // RNE
  return __builtin_bit_cast(unsigned short, h);
}
__device__ __forceinline__ void gll16(const void* g, unsigned short* l) {
  __builtin_amdgcn_global_load_lds(
      (const __attribute__((address_space(1))) void*)g,
      (__attribute__((address_space(3))) void*)l, 16, 0, 0);
}

// ------ pack W[K][N] (fp32) -> Bf fragment-ordered bf16 --------------------
__global__ __launch_bounds__(256)
void pack_bf(const float* __restrict__ W, unsigned short* __restrict__ Bf,
             int N, int ngroups) {
  int g = blockIdx.x * 256 + threadIdx.x;
  if (g >= ngroups) return;
  int lane = g & 63;
  int kb   = (g >> 6) & 1;
  int nj   = (g >> 7) & 3;
  int wn   = (g >> 9) & 1;
  int kt   = (g >> 10) & 7;
  int tn   = g >> 13;
  int n  = tn * 128 + wn * 64 + nj * 16 + (lane & 15);
  int k0 = kt * 64 + (kb * 4 + (lane >> 4)) * 8;
  u16x8 u;
  #pragma unroll
  for (int e = 0; e < 8; ++e) u[e] = f2b(W[(long)(k0 + e) * N + n]);
  ((u16x8*)Bf)[g] = u;
}

#define BAR() __builtin_amdgcn_s_barrier()
#define LGK0() do { asm volatile("s_waitcnt lgkmcnt(0)" ::: "memory"); \
                    __builtin_amdgcn_sched_barrier(0); } while (0)
#define LGKW() asm volatile("s_waitcnt lgkmcnt(0)" ::: "memory")
#define VM(N) asm volatile("s_waitcnt vmcnt(" #N ")" ::: "memory")

// bf[nj][kb] <- packed B frags for K-tile KT (8 coalesced 16B loads, L2-hot)
#define LDBG(KT) do { \
  const short8* _bp = (const short8*)(Bfw + (long)(KT) * 8192) + lane; \
  _Pragma("unroll") for (int nj = 0; nj < 4; ++nj) \
    _Pragma("unroll") for (int kb = 0; kb < 2; ++kb) \
      bf[nj][kb] = _bp[(nj*2 + kb) * 64]; \
} while (0)

// af[ii][kb] <- A row wm*64 + ii*16 + lr, 16B chunk (kb*4+lk)^(row&7)
#define LDA_B16(ABASE) do { \
  const char* _ba = (const char*)(ABASE); \
  _Pragma("unroll") for (int ii = 0; ii < 4; ++ii) { \
    int _row = wm*64 + ii*16 + lr; \
    _Pragma("unroll") for (int kb = 0; kb < 2; ++kb) \
      af[ii][kb] = *(const short8*)(_ba + _row*128 + (((kb*4+lk) ^ lr7) * 16)); \
  } \
} while (0)

#define MMA_ALL() do { \
  __builtin_amdgcn_s_setprio(1); \
  _Pragma("unroll") for (int ii = 0; ii < 4; ++ii) \
    _Pragma("unroll") for (int jj = 0; jj < 4; ++jj) \
      _Pragma("unroll") for (int kb = 0; kb < 2; ++kb) \
        acc[ii][jj] = __builtin_amdgcn_mfma_f32_16x16x32_bf16( \
            af[ii][kb], bf[jj][kb], acc[ii][jj], 0, 0, 0); \
  __builtin_amdgcn_s_setprio(0); \
} while (0)

// ====== GEMM1: fp32 A -> regs -> cvt -> bf16 LDS (fused convert) ===========
// LDS identical to R8's bf16 A-dbuf (16KB/tile): read path proven 0-conflict.
// R9 spill fixed: __launch_bounds__(256,2) -> 256-VGPR cap; live set
// acc(64)+ra(32)+af(16)+bf(16)+addr ~ 180 fits.  2 blocks/CU.
// Per K-tile kt (buf b = kt&1), ONE barrier:
//   issue ra <- A_f32(kt+2)   [8 dwordx4; in flight across whole tile]
//   LDBG(kt) ; LDA_B16(buf b) ; lgkm0 ; MFMA   [compiler waits only bf]
//   BAR   [all waves done reading buf b]
//   cvt ra -> ds_write buf b x4 ; lgkm0(own writes)
// Cross-wave visibility of writes(kt) for readers at kt+2: every wave's
// lgkm0 precedes its arrival at tile kt+1's BAR, which precedes any kt+2
// read. WAR on buf b: writes follow kt's BAR which follows all reads.
// Register WAR (ra reuse next tile): loads issue after cvt consumed (in-order
// issue). Prologue stages T0,T1 through ra serially (compiler vmcnt-waits).

__device__ __forceinline__ void loadA_f32(const float* __restrict__ G,
                                          long rowBase, int K, int kt,
                                          int tid, float4v (&ra)[8]) {
  int r  = tid >> 3;                       // 0..31
  int ch = tid & 7;                        // 8 x 32B covers a 256B row
  const float* s = G + (rowBase + r) * (long)K + kt * 64 + ch * 8;
  #pragma unroll
  for (int q = 0; q < 4; ++q) {            // rows r, r+32, r+64, r+96
    const float4v* p = (const float4v*)(s + (long)32 * q * K);
    ra[2 * q]     = p[0];
    ra[2 * q + 1] = p[1];
  }
}
__device__ __forceinline__ void writeA_bf16(unsigned short* ldsA, int tid,
                                            const float4v (&ra)[8]) {
  int r  = tid >> 3;
  int ch = tid & 7;
  #pragma unroll
  for (int q = 0; q < 4; ++q) {
    int row = r + 32 * q;
    const float4v a = ra[2 * q], b = ra[2 * q + 1];
    u16x8 u;
    u[0] = f2b(a.x); u[1] = f2b(a.y); u[2] = f2b(a.z); u[3] = f2b(a.w);
    u[4] = f2b(b.x); u[5] = f2b(b.y); u[6] = f2b(b.z); u[7] = f2b(b.w);
    *(u16x8*)(ldsA + row * 64 + ((ch ^ (row & 7)) * 8)) = u;   // swizzled write
  }
}

#define G1TILE(ABUF, KT, STG) do { \
  if (STG) loadA_f32(Ag, mBase, K, (KT) + 2, tid, ra); \
  LDBG(KT); \
  LDA_B16(ABUF); \
  LGK0(); \
  MMA_ALL(); \
  BAR(); \
  if (STG) { writeA_bf16(ABUF, tid, ra); LGKW(); } \
} while (0)

__global__ __launch_bounds__(256, 2)
void gemm128f(const float* __restrict__ Ag,
              const unsigned short* __restrict__ Bf,
              const float* __restrict__ bias,
              unsigned short* __restrict__ Cout,
              int M, int N, int K, int tilesN) {
  __shared__ __align__(16) unsigned short lds[16384];   // 32 KiB bf16 A dbuf

  int tid = threadIdx.x;
  int nwg = gridDim.x;
  int cpx = nwg >> 3;
  int wg  = ((int)blockIdx.x & 7) * cpx + ((int)blockIdx.x >> 3);  // XCD swizzle
  int tm = wg / tilesN, tn = wg % tilesN;
  long mBase = (long)tm * 128;
  long nBase = (long)tn * 128;

  int lane = tid & 63, wave = tid >> 6;
  int wm = wave >> 1, wn = wave & 1;
  int lr = lane & 15, lk = lane >> 4, lr7 = lr & 7;

  const unsigned short* Bfw = Bf + (long)tn * 65536 + wn * 4096;

  unsigned short* A0 = lds;              // buf0 A (128x64 bf16)
  unsigned short* A1 = lds + 8192;       // buf1 A

  f32x4 acc[4][4];
  #pragma unroll
  for (int i = 0; i < 4; ++i)
    #pragma unroll
    for (int j = 0; j < 4; ++j) acc[i][j] = (f32x4){0.f, 0.f, 0.f, 0.f};

  short8 af[4][2], bf[4][2];
  float4v ra[8];

  // prologue: T0 -> buf0, T1 -> buf1 (reg round-trips; compiler vmcnt-waits)
  loadA_f32(Ag, mBase, K, 0, tid, ra);
  writeA_bf16(A0, tid, ra);
  loadA_f32(Ag, mBase, K, 1, tid, ra);
  writeA_bf16(A1, tid, ra);
  LGKW(); BAR();

  #pragma unroll 1
  for (int i = 0; i < 3; ++i) {
    G1TILE(A0, 2*i,     true);     // stages T(2i+2) into A0
    G1TILE(A1, 2*i + 1, true);     // stages T(2i+3) into A1
  }
  G1TILE(A0, 6, false);
  G1TILE(A1, 7, false);

  // epilogue: C/D layout col = lane&15, row = (lane>>4)*4 + r ; bf16 out
  long rowb = mBase + wm * 64 + (lane >> 4) * 4;
  int  colb = (int)nBase + wn * 64 + lr;
  #pragma unroll
  for (int mi = 0; mi < 4; ++mi)
    #pragma unroll
    for (int nj = 0; nj < 4; ++nj) {
      int col = colb + nj * 16;
      float bv = bias[col];
      #pragma unroll
      for (int r = 0; r < 4; ++r)
        Cout[(rowb + mi * 16 + r) * (long)N + col] = f2b(acc[mi][nj][r] + bv);
    }
}

// ============ GEMM2: R8-verbatim bf16-A gll16 path, fp32 out ===============
__device__ __forceinline__ void stage_tileA(const unsigned short* __restrict__ G,
                                            long rowBase, int K, int kt,
                                            unsigned short* ldsDst, int tid) {
  int r  = tid >> 3;                       // 0..31
  int ch = (tid & 7) ^ (r & 7);            // inverse-swizzled source chunk
  const unsigned short* s0 = G + (rowBase + r) * (long)K + kt * 64 + ch * 8;
  unsigned short* d0 = ldsDst + tid * 8;
  #pragma unroll
  for (int q = 0; q < 4; ++q)              // rows r, r+32, r+64, r+96
    gll16(s0 + (long)32 * q * K, d0 + 2048 * q);
}

#define G2TILE(ABUF, KT, STG, VMARG) do { \
  LDBG(KT); \
  LDA_B16(ABUF); \
  LGK0(); \
  BAR(); \
  if (STG) stage_tileA(Ag, mBase, K, (KT) + 2, ABUF, tid); \
  VMARG; \
  MMA_ALL(); \
  BAR(); \
} while (0)

__global__ __launch_bounds__(256, 3)
void gemm128b(const unsigned short* __restrict__ Ag,
              const unsigned short* __restrict__ Bf,
              const float* __restrict__ bias,
              float* __restrict__ Cout,
              int M, int N, int K, int tilesN) {
  __shared__ __align__(16) unsigned short lds[16384];   // 32 KiB (A dbuf)

  int tid = threadIdx.x;
  int nwg = gridDim.x;
  int cpx = nwg >> 3;
  int wg  = ((int)blockIdx.x & 7) * cpx + ((int)blockIdx.x >> 3);  // XCD swizzle
  int tm = wg / tilesN, tn = wg % tilesN;
  long mBase = (long)tm * 128;
  long nBase = (long)tn * 128;

  int lane = tid & 63, wave = tid >> 6;
  int wm = wave >> 1, wn = wave & 1;
  int lr = lane & 15, lk = lane >> 4, lr7 = lr & 7;

  const unsigned short* Bfw = Bf + (long)tn * 65536 + wn * 4096;

  unsigned short* A0 = lds;              // buf0 A (128x64 bf16)
  unsigned short* A1 = lds + 8192;       // buf1 A

  f32x4 acc[4][4];
  #pragma unroll
  for (int i = 0; i < 4; ++i)
    #pragma unroll
    for (int j = 0; j < 4; ++j) acc[i][j] = (f32x4){0.f, 0.f, 0.f, 0.f};

  short8 af[4][2], bf[4][2];

  stage_tileA(Ag, mBase, K, 0, A0, tid);
  stage_tileA(Ag, mBase, K, 1, A1, tid);
  VM(4);                       // A(0) landed (A(1)'s 4 in flight)
  BAR();

  #pragma unroll 1
  for (int i = 0; i < 3; ++i) {
    G2TILE(A0, 2*i,     true, VM(4));
    G2TILE(A1, 2*i + 1, true, VM(4));
  }
  G2TILE(A0, 6, false, VM(0));
  G2TILE(A1, 7, false, VM(0));

  long rowb = mBase + wm * 64 + (lane >> 4) * 4;
  int  colb = (int)nBase + wn * 64 + lr;
  #pragma unroll
  for (int mi = 0; mi < 4; ++mi)
    #pragma unroll
    for (int nj = 0; nj < 4; ++nj) {
      int col = colb + nj * 16;
      float bv = bias[col];
      #pragma unroll
      for (int r = 0; r < 4; ++r)
        Cout[(rowb + mi * 16 + r) * (long)N + col] = acc[mi][nj][r] + bv;
    }
}

// ---------------- neighborhood attention: 1 thread per (b,l,h) ------------
__global__ __launch_bounds__(256)
void natt(const unsigned short* __restrict__ qkv, const float* __restrict__ rpb,
          unsigned short* __restrict__ out) {
  int tid = blockIdx.x * 256 + threadIdx.x;
  int h = tid & 15;
  int l = (tid >> 4) & (NL - 1);
  int b = tid >> 16;
  const float scale = 0.17677669529663687f;

  long qb = ((long)(b * NL + l) * 3) * NC + h * HD;
  float q[HD];
  {
    const u16x8* q8 = (const u16x8*)(qkv + qb);
    #pragma unroll
    for (int w = 0; w < 4; ++w) {
      u16x8 u = q8[w];
      #pragma unroll
      for (int e = 0; e < 8; ++e) q[w * 8 + e] = b2f(u[e]) * scale;
    }
  }

  int ni = l - KHALF;
  if (ni < 0) ni = 0;
  if (ni > NL - KW) ni = NL - KW;
  const float* rb = rpb + h * (2 * KW - 1) + (ni - l + KW - 1);

  float p[KW];
  float mx = -1e30f;
  #pragma unroll
  for (int j = 0; j < KW; ++j) {
    long kb = ((long)(b * NL + ni + j) * 3 + 1) * NC + h * HD;
    const u16x8* k8 = (const u16x8*)(qkv + kb);
    float s = 0.f;
    #pragma unroll
    for (int w = 0; w < 4; ++w) {
      u16x8 u = k8[w];
      #pragma unroll
      for (int e = 0; e < 8; ++e) s += q[w * 8 + e] * b2f(u[e]);
    }
    s += rb[j];
    p[j] = s;
    mx = fmaxf(mx, s);
  }

  float sum = 0.f;
  #pragma unroll
  for (int j = 0; j < KW; ++j) { p[j] = __expf(p[j] - mx); sum += p[j]; }
  float inv = 1.0f / sum;

  float o[HD];
  #pragma unroll
  for (int d = 0; d < HD; ++d) o[d] = 0.f;
  #pragma unroll
  for (int j = 0; j < KW; ++j) {
    long vb = ((long)(b * NL + ni + j) * 3 + 2) * NC + h * HD;
    const u16x8* v8 = (const u16x8*)(qkv + vb);
    float wj = p[j] * inv;
    #pragma unroll
    for (int w = 0; w < 4; ++w) {
      u16x8 u = v8[w];
      #pragma unroll
      for (int e = 0; e < 8; ++e) o[w * 8 + e] += wj * b2f(u[e]);
    }
  }

  unsigned short* op = out + (long)(b * NL + l) * NC + h * HD;
  #pragma unroll
  for (int w = 0; w < 4; ++w) {
    u16x8 u;
    #pragma unroll
    for (int e = 0; e < 8; ++e) u[e] = f2b(o[w * 8 + e]);
    *((u16x8*)(op + w * 8)) = u;
  }
}

// ---------------------------------------------------------------------------
extern "C" void kernel_launch(void* const* d_in, const int* in_sizes, int n_in,
                              void* d_out, int out_size, void* d_ws, size_t ws_size,
                              hipStream_t stream) {
  const float* x      = (const float*)d_in[0];
  const float* qkv_w  = (const float*)d_in[1];
  const float* qkv_b  = (const float*)d_in[2];
  const float* rpb    = (const float*)d_in[3];
  const float* proj_w = (const float*)d_in[4];
  const float* proj_b = (const float*)d_in[5];
  float* out = (float*)d_out;

  char* ws = (char*)d_ws;
  unsigned short* Bf1  = (unsigned short*)(ws);              //  1,572,864 B
  unsigned short* Bf2  = (unsigned short*)(ws + 1572864);    //    524,288 B
  unsigned short* qkvo = (unsigned short*)(ws + 2097152);    // 50,331,648 B
  unsigned short* attno= (unsigned short*)(ws + 52428800);   // 16,777,216 B

  // pack weights into MFMA-fragment order
  pack_bf<<<dim3(384), dim3(256), 0, stream>>>(qkv_w, Bf1, 1536, 98304);
  pack_bf<<<dim3(128), dim3(256), 0, stream>>>(proj_w, Bf2, 512, 32768);
  // qkv = x @ qkv_w + b  (fp32 A, fused reg convert; bf16 out)
  gemm128f<<<dim3(1536), dim3(256), 0, stream>>>(x, Bf1, qkv_b, qkvo,
                                                 NM, 1536, 512, 12);
  natt<<<dim3(1024), dim3(256), 0, stream>>>(qkvo, rpb, attno);
  // out = attn @ proj_w + b  (bf16 A via gll16; fp32 out)
  gemm128b<<<dim3(512), dim3(256), 0, stream>>>(attno, Bf2, proj_b, out,
                                                NM, 512, 512, 4);
}